// Round 3
// baseline (269.232 us; speedup 1.0000x reference)
//
#include <hip/hip_runtime.h>

typedef unsigned short u16;
typedef unsigned int u32;
typedef __attribute__((ext_vector_type(8))) _Float16 half8;
typedef __attribute__((ext_vector_type(16))) float f32x16;

#define MFMA32(A, B, C) __builtin_amdgcn_mfma_f32_32x32x16_f16(A, B, C, 0, 0, 0)

constexpr int BN = 8;     // batches
constexpr int S = 4096;   // seq len (enc and dec)
constexpr int D = 256;    // feature dim
constexpr int KB = 32;    // K/V tile rows per iteration
constexpr int NT = S / KB;           // 128 tiles
constexpr int TILE_U16 = KB * D;     // 8192 u16 = 16 KiB per tile image

__device__ __forceinline__ u32 pk2h(float a, float b) {
  union { _Float16 h[2]; u32 u; } x;
  x.h[0] = (_Float16)a; x.h[1] = (_Float16)b;
  return x.u;
}

__device__ __forceinline__ void gload_lds16(const void* g, void* l) {
  __builtin_amdgcn_global_load_lds((__attribute__((address_space(1))) void*)(void*)g,
                                   (__attribute__((address_space(3))) void*)l, 16, 0, 0);
}

// ---------------------------------------------------------------------------
// Convert enc (f32) into MFMA-fragment-ordered f16 tile images so that every
// attn ds_read_b128 is lane-linear (zero bank conflicts) and staging is a
// plain linear global_load_lds copy.
//
// enc_ws  (QK^T A-operand), per (b, tile t): group(c,h,i) at offset
//   ((c*2+h)*32 + i)*8 u16, holding enc[t*32+i][c*16+h*8 + 0..7].
// encT_ws (PV  A-operand), per (b, tile t): group(dsub,ic,h,dd) at offset
//   (((dsub*2+ic)*2+h)*32 + dd)*8 u16, holding enc[t*32+ic*16+h*8+j][dsub*32+dd], j=0..7.
// ---------------------------------------------------------------------------
__global__ __launch_bounds__(256) void convert_enc(const float* __restrict__ enc,
                                                   u16* __restrict__ enc_ws,
                                                   u16* __restrict__ encT_ws) {
  const int blk = blockIdx.x;
  const int b = blk & 7;
  const int tp = blk >> 3;  // tile pair 0..63
  const int tid = threadIdx.x;

  const float* encb = enc + (size_t)b * S * D;

  // ---- phase A: enc_ws, 2 tiles x 1024 groups, 8 groups/thread ----
#pragma unroll
  for (int it = 0; it < 8; ++it) {
    int gg = it * 256 + tid;        // 0..2047
    int t = tp * 2 + (gg >> 10);
    int g = gg & 1023;              // (c*2+h)*32 + i
    int i = g & 31;
    int ch = g >> 5;                // c*2+h
    int d0 = ch * 8;
    const float* src = encb + (size_t)(t * 32 + i) * D + d0;
    float4 x = *(const float4*)src;
    float4 y = *(const float4*)(src + 4);
    uint4 o;
    o.x = pk2h(x.x, x.y); o.y = pk2h(x.z, x.w);
    o.z = pk2h(y.x, y.y); o.w = pk2h(y.z, y.w);
    *(uint4*)(enc_ws + (size_t)(b * NT + t) * TILE_U16 + g * 8) = o;
  }

  // ---- phase B: encT_ws, 2 tiles x 128 blocklets (8i x 8d), 1/thread ----
  {
    int t = tp * 2 + (tid >> 7);
    int r = tid & 127;
    int o = r >> 5;       // i-oct: ic = o>>1, h = o&1
    int e = r & 31;       // d-oct
    int i0 = o * 8;
    int d0 = e * 8;
    float v[8][8];
#pragma unroll
    for (int rr = 0; rr < 8; ++rr) {
      const float* src = encb + (size_t)(t * 32 + i0 + rr) * D + d0;
      *(float4*)&v[rr][0] = *(const float4*)src;
      *(float4*)&v[rr][4] = *(const float4*)(src + 4);
    }
    int dsub = e >> 2;
    u16* dst = encT_ws + (size_t)(b * NT + t) * TILE_U16 + ((dsub * 4 + o) * 32 + (e & 3) * 8) * 8;
#pragma unroll
    for (int k = 0; k < 8; ++k) {
      uint4 q;
      q.x = pk2h(v[0][k], v[1][k]); q.y = pk2h(v[2][k], v[3][k]);
      q.z = pk2h(v[4][k], v[5][k]); q.w = pk2h(v[6][k], v[7][k]);
      *(uint4*)(dst + k * 8) = q;   // dd = (e&3)*8 + k -> consecutive 16B groups
    }
  }
}

// ---------------------------------------------------------------------------
// Flash attention: Q=dec, K=V=enc, 32x32x16 f16 MFMA.
// 512 blocks x 128 thr (2 waves x 32 q-rows). KB=32. LDS 64 KiB -> 2 blk/CU.
// Swapped QK^T (S^T = enc.Q^T), transposed O accumulate, log2-domain softmax.
// ---------------------------------------------------------------------------
__global__ __launch_bounds__(128, 1) void attn_kernel(const u16* __restrict__ enc_ws,
                                                      const u16* __restrict__ encT_ws,
                                                      const float* __restrict__ dec,
                                                      float* __restrict__ out) {
  __shared__ u16 enc_s[2][TILE_U16];   // 2 x 16 KiB
  __shared__ u16 encT_s[2][TILE_U16];  // 2 x 16 KiB

  const int tid = threadIdx.x;
  const int w = tid >> 6;        // wave 0..1
  const int lane = tid & 63;
  const int h = lane >> 5;       // half-wave
  const int l31 = lane & 31;

  const int blk = blockIdx.x;
  const int b = blk & 7;               // batch -> XCD affinity
  const int q0 = (blk >> 3) << 6;      // QBLK = 64
  const int qw = q0 + w * 32;          // this wave's first q row

  const u16* encb = enc_ws + (size_t)b * NT * TILE_U16;
  const u16* encTb = encT_ws + (size_t)b * NT * TILE_U16;
  const float* decb = dec + (size_t)b * S * D;

  // ---- Q fragments (B-operand): lane holds q=l31 (col), k=c*16+h*8+j ----
  // pre-scaled by log2(e) so softmax runs in exp2 domain
  const float LOG2E = 1.4426950408889634f;
  half8 qf[16];
#pragma unroll
  for (int c = 0; c < 16; ++c) {
    const float* p = decb + (size_t)(qw + l31) * D + c * 16 + h * 8;
    float4 x = *(const float4*)p;
    float4 y = *(const float4*)(p + 4);
    union { u32 u[4]; half8 v; } uu;
    uu.u[0] = pk2h(x.x * LOG2E, x.y * LOG2E);
    uu.u[1] = pk2h(x.z * LOG2E, x.w * LOG2E);
    uu.u[2] = pk2h(y.x * LOG2E, y.y * LOG2E);
    uu.u[3] = pk2h(y.z * LOG2E, y.w * LOG2E);
    qf[c] = uu.v;
  }

  // ---- staging: pure linear copy of both 16 KiB tile images ----
  auto stage = [&](int buf, int t) {
    const char* g0 = (const char*)(encb + (size_t)t * TILE_U16);
    const char* g1 = (const char*)(encTb + (size_t)t * TILE_U16);
    char* l0 = (char*)&enc_s[buf][0];
    char* l1 = (char*)&encT_s[buf][0];
#pragma unroll
    for (int it = 0; it < 8; ++it) {
      int off = w * 8192 + it * 1024;
      gload_lds16(g0 + off + lane * 16, l0 + off);
      gload_lds16(g1 + off + lane * 16, l1 + off);
    }
  };

  f32x16 acc[8] = {};   // O^T: [dsub]; lane: q=l31, d=dsub*32+(r&3)+8*(r>>2)+4h
  float mrun = -1e30f;  // running max (log2 domain)
  float lrun = 0.f;

  stage(0, 0);
  __syncthreads();

  for (int t = 0; t < NT; ++t) {
    const int cur = t & 1;
    if (t + 1 < NT) stage(cur ^ 1, t + 1);

    // ---- S^T = enc . Q^T : lane-linear A-frag reads ----
    f32x16 st = {};  // lane: q=l31 (col), i=(r&3)+8*(r>>2)+4h
    const char* eb = (const char*)&enc_s[cur][0];
#pragma unroll
    for (int c = 0; c < 16; ++c) {
      half8 af = *(const half8*)(eb + (c * 2 + h) * 512 + l31 * 16);
      st = MFMA32(af, qf[c], st);
    }

    // ---- online softmax over i (log2 domain), defer-max THR=8*log2e ----
    float tm = st[0];
#pragma unroll
    for (int r = 1; r < 16; ++r) tm = fmaxf(tm, st[r]);
    tm = fmaxf(tm, __shfl_xor(tm, 32));
    if (__any(tm > mrun + 11.5f)) {
      float mnew = fmaxf(mrun, tm);
      float alpha = __builtin_amdgcn_exp2f(mrun - mnew);
      mrun = mnew;
      lrun *= alpha;
#pragma unroll
      for (int ds = 0; ds < 8; ++ds)
#pragma unroll
        for (int r = 0; r < 16; ++r) acc[ds][r] *= alpha;
    }
    float p[16];
    float rs = 0.f;
#pragma unroll
    for (int r = 0; r < 16; ++r) {
      p[r] = __builtin_amdgcn_exp2f(st[r] - mrun);
      rs += p[r];
    }
    rs += __shfl_xor(rs, 32);
    lrun += rs;

    // ---- pack P^T to f16; pkw[rq*2+w2] covers i = 8*rq + 4h + 2*w2 + {0,1} ----
    u32 pkw[8];
#pragma unroll
    for (int rq = 0; rq < 4; ++rq) {
      pkw[rq * 2 + 0] = pk2h(p[rq * 4 + 0], p[rq * 4 + 1]);
      pkw[rq * 2 + 1] = pk2h(p[rq * 4 + 2], p[rq * 4 + 3]);
    }
    // ---- B-frag(ic): lane needs i = ic*16 + 8h + {0..7} ----
    half8 bfr[2];
#pragma unroll
    for (int ic = 0; ic < 2; ++ic) {
      u32 own0 = pkw[(2 * ic + h) * 2 + 0];
      u32 own1 = pkw[(2 * ic + h) * 2 + 1];
      u32 send0 = pkw[(2 * ic + 1 - h) * 2 + 0];
      u32 send1 = pkw[(2 * ic + 1 - h) * 2 + 1];
      u32 r0 = (u32)__shfl_xor((int)send0, 32);
      u32 r1 = (u32)__shfl_xor((int)send1, 32);
      union { u32 u[4]; half8 v; } bb;
      bb.u[0] = h ? r0 : own0;
      bb.u[1] = h ? r1 : own1;
      bb.u[2] = h ? own0 : r0;
      bb.u[3] = h ? own1 : r1;
      bfr[ic] = bb.v;
    }

    // ---- O^T += encT . P^T : lane-linear A-frag reads ----
    const char* tb = (const char*)&encT_s[cur][0];
#pragma unroll
    for (int ic = 0; ic < 2; ++ic) {
#pragma unroll
      for (int ds = 0; ds < 8; ++ds) {
        half8 vf = *(const half8*)(tb + ((ds * 2 + ic) * 2 + h) * 512 + l31 * 16);
        acc[ds] = MFMA32(vf, bfr[ic], acc[ds]);
      }
    }

    __syncthreads();  // all waves done reading cur; next-tile stage writes landed
  }

  // ---- epilogue: divide by l, store O ----
  {
    float inv = 1.0f / lrun;
    const int q = qw + l31;
    float* orow = out + ((size_t)(b * S + q)) * D;
#pragma unroll
    for (int ds = 0; ds < 8; ++ds) {
#pragma unroll
      for (int rq = 0; rq < 4; ++rq) {
        int d = ds * 32 + rq * 8 + h * 4;
        float4 o;
        o.x = acc[ds][rq * 4 + 0] * inv;
        o.y = acc[ds][rq * 4 + 1] * inv;
        o.z = acc[ds][rq * 4 + 2] * inv;
        o.w = acc[ds][rq * 4 + 3] * inv;
        *(float4*)(orow + d) = o;
      }
    }
  }
}

// ---------------------------------------------------------------------------
extern "C" void kernel_launch(void* const* d_in, const int* in_sizes, int n_in,
                              void* d_out, int out_size, void* d_ws, size_t ws_size,
                              hipStream_t stream) {
  const float* enc = (const float*)d_in[0];
  const float* dec = (const float*)d_in[1];
  float* out = (float*)d_out;

  u16* enc_ws = (u16*)d_ws;                            // 16 MiB
  u16* encT_ws = enc_ws + (size_t)BN * NT * TILE_U16;  // 16 MiB

  convert_enc<<<BN * (S / 64), 256, 0, stream>>>(enc, enc_ws, encT_ws);
  attn_kernel<<<BN * (S / 64), 128, 0, stream>>>(enc_ws, encT_ws, dec, out);
}

// Round 4
// 186.925 us; speedup vs baseline: 1.4403x; 1.4403x over previous
//
#include <hip/hip_runtime.h>

typedef unsigned short u16;
typedef unsigned int u32;
typedef __attribute__((ext_vector_type(8))) _Float16 half8;
typedef __attribute__((ext_vector_type(16))) float f32x16;

#define MFMA32(A, B, C) __builtin_amdgcn_mfma_f32_32x32x16_f16(A, B, C, 0, 0, 0)

constexpr int BN = 8;     // batches
constexpr int S = 4096;   // seq len (enc and dec)
constexpr int D = 256;    // feature dim
constexpr int KB = 32;    // K/V tile rows per iteration
constexpr int NT = S / KB;           // 128 tiles
constexpr int TILE_U16 = KB * D;     // 8192 u16 = 16 KiB per tile image

__device__ __forceinline__ u32 pk2h(float a, float b) {
  union { _Float16 h[2]; u32 u; } x;
  x.h[0] = (_Float16)a; x.h[1] = (_Float16)b;
  return x.u;
}

__device__ __forceinline__ void gload_lds16(const void* g, void* l) {
  __builtin_amdgcn_global_load_lds((__attribute__((address_space(1))) void*)(void*)g,
                                   (__attribute__((address_space(3))) void*)l, 16, 0, 0);
}

// ---------------------------------------------------------------------------
// Convert enc (f32) into MFMA-fragment-ordered f16 tile images (unchanged from
// round 3 — validated): every attn ds_read_b128 is lane-linear, staging is a
// plain linear global_load_lds copy.
// ---------------------------------------------------------------------------
__global__ __launch_bounds__(256) void convert_enc(const float* __restrict__ enc,
                                                   u16* __restrict__ enc_ws,
                                                   u16* __restrict__ encT_ws) {
  const int blk = blockIdx.x;
  const int b = blk & 7;
  const int tp = blk >> 3;  // tile pair 0..63
  const int tid = threadIdx.x;

  const float* encb = enc + (size_t)b * S * D;

  // ---- phase A: enc_ws, 2 tiles x 1024 groups, 8 groups/thread ----
#pragma unroll
  for (int it = 0; it < 8; ++it) {
    int gg = it * 256 + tid;        // 0..2047
    int t = tp * 2 + (gg >> 10);
    int g = gg & 1023;              // (c*2+h)*32 + i
    int i = g & 31;
    int ch = g >> 5;                // c*2+h
    int d0 = ch * 8;
    const float* src = encb + (size_t)(t * 32 + i) * D + d0;
    float4 x = *(const float4*)src;
    float4 y = *(const float4*)(src + 4);
    uint4 o;
    o.x = pk2h(x.x, x.y); o.y = pk2h(x.z, x.w);
    o.z = pk2h(y.x, y.y); o.w = pk2h(y.z, y.w);
    *(uint4*)(enc_ws + (size_t)(b * NT + t) * TILE_U16 + g * 8) = o;
  }

  // ---- phase B: encT_ws, 2 tiles x 128 blocklets (8i x 8d), 1/thread ----
  {
    int t = tp * 2 + (tid >> 7);
    int r = tid & 127;
    int o = r >> 5;       // i-oct: ic = o>>1, h = o&1
    int e = r & 31;       // d-oct
    int i0 = o * 8;
    int d0 = e * 8;
    float v[8][8];
#pragma unroll
    for (int rr = 0; rr < 8; ++rr) {
      const float* src = encb + (size_t)(t * 32 + i0 + rr) * D + d0;
      *(float4*)&v[rr][0] = *(const float4*)src;
      *(float4*)&v[rr][4] = *(const float4*)(src + 4);
    }
    int dsub = e >> 2;
    u16* dst = encT_ws + (size_t)(b * NT + t) * TILE_U16 + ((dsub * 4 + o) * 32 + (e & 3) * 8) * 8;
#pragma unroll
    for (int k = 0; k < 8; ++k) {
      uint4 q;
      q.x = pk2h(v[0][k], v[1][k]); q.y = pk2h(v[2][k], v[3][k]);
      q.z = pk2h(v[4][k], v[5][k]); q.w = pk2h(v[6][k], v[7][k]);
      *(uint4*)(dst + k * 8) = q;
    }
  }
}

// ---------------------------------------------------------------------------
// Flash attention, 8-wave blocks with in-block split-K.
// 256 blocks x 512 thr. QBLK=128 (4 waves x 32 q) x 2 K-streams (kh=w>>2).
// Stream kh processes tiles t = 2j+kh, j=0..63, independently (own m,l,acc);
// merge at the end through LDS. 128 KiB LDS -> 1 block/CU = 8 waves/CU.
// ---------------------------------------------------------------------------
__global__ __launch_bounds__(512, 2) void attn_kernel(const u16* __restrict__ enc_ws,
                                                      const u16* __restrict__ encT_ws,
                                                      const float* __restrict__ dec,
                                                      float* __restrict__ out) {
  __shared__ u16 lds[2][2][2 * TILE_U16];  // [stream][buf][enc_img | encT_img] = 128 KiB

  const int tid = threadIdx.x;
  const int w = tid >> 6;        // wave 0..7
  const int wq = w & 3;          // q-chunk within block
  const int kh = w >> 2;         // K-stream
  const int lane = tid & 63;
  const int h = lane >> 5;       // half-wave
  const int l31 = lane & 31;

  const int blk = blockIdx.x;
  const int b = blk & 7;               // batch -> XCD affinity
  const int q0 = (blk >> 3) << 7;      // QBLK = 128
  const int qw = q0 + wq * 32;         // this wave's first q row

  const u16* encb = enc_ws + (size_t)b * NT * TILE_U16;
  const u16* encTb = encT_ws + (size_t)b * NT * TILE_U16;
  const float* decb = dec + (size_t)b * S * D;

  // ---- Q fragments (B-operand): lane holds q=l31 (col), k=c*16+h*8+j ----
  const float LOG2E = 1.4426950408889634f;
  half8 qf[16];
#pragma unroll
  for (int c = 0; c < 16; ++c) {
    const float* p = decb + (size_t)(qw + l31) * D + c * 16 + h * 8;
    float4 x = *(const float4*)p;
    float4 y = *(const float4*)(p + 4);
    union { u32 u[4]; half8 v; } uu;
    uu.u[0] = pk2h(x.x * LOG2E, x.y * LOG2E);
    uu.u[1] = pk2h(x.z * LOG2E, x.w * LOG2E);
    uu.u[2] = pk2h(y.x * LOG2E, y.y * LOG2E);
    uu.u[3] = pk2h(y.z * LOG2E, y.w * LOG2E);
    qf[c] = uu.v;
  }

  // ---- staging: 4 waves of a stream stage its 32 KiB (8 KiB each), linear ----
  auto stage = [&](int buf, int t) {
    const u16* gimg = (wq < 2) ? (encb + (size_t)t * TILE_U16)
                               : (encTb + (size_t)t * TILE_U16);
    char* limg = (char*)&lds[kh][buf][(wq < 2) ? 0 : TILE_U16];
    const int half = (wq & 1) * 8192;
#pragma unroll
    for (int it = 0; it < 8; ++it) {
      int off = half + it * 1024;
      gload_lds16((const char*)gimg + off + lane * 16, limg + off);
    }
  };

  f32x16 acc[8] = {};   // O^T: [dsub]; lane: q=l31, d=dsub*32+(r&3)+8*(r>>2)+4h
  float mrun = -1e30f;  // running max (log2 domain)
  float lrun = 0.f;

  stage(0, kh);
  __syncthreads();

  for (int j = 0; j < NT / 2; ++j) {
    const int cur = j & 1;
    if (j + 1 < NT / 2) stage(cur ^ 1, 2 * (j + 1) + kh);

    // ---- S^T = enc . Q^T : 2 independent MFMA chains ----
    f32x16 s0 = {}, s1 = {};
    const char* eb = (const char*)&lds[kh][cur][0];
#pragma unroll
    for (int c = 0; c < 16; c += 2) {
      half8 a0 = *(const half8*)(eb + ((c + 0) * 2 + h) * 512 + l31 * 16);
      half8 a1 = *(const half8*)(eb + ((c + 1) * 2 + h) * 512 + l31 * 16);
      s0 = MFMA32(a0, qf[c + 0], s0);
      s1 = MFMA32(a1, qf[c + 1], s1);
    }
    f32x16 st = s0 + s1;

    // ---- online softmax over i (log2 domain), defer-max; tree reductions ----
    float x0 = fmaxf(st[0], st[1]), x1 = fmaxf(st[2], st[3]);
    float x2 = fmaxf(st[4], st[5]), x3 = fmaxf(st[6], st[7]);
    float x4 = fmaxf(st[8], st[9]), x5 = fmaxf(st[10], st[11]);
    float x6 = fmaxf(st[12], st[13]), x7 = fmaxf(st[14], st[15]);
    x0 = fmaxf(x0, x1); x2 = fmaxf(x2, x3); x4 = fmaxf(x4, x5); x6 = fmaxf(x6, x7);
    x0 = fmaxf(x0, x2); x4 = fmaxf(x4, x6);
    float tm = fmaxf(x0, x4);
    tm = fmaxf(tm, __shfl_xor(tm, 32));
    if (__any(tm > mrun + 11.5f)) {
      float mnew = fmaxf(mrun, tm);
      float alpha = __builtin_amdgcn_exp2f(mrun - mnew);
      mrun = mnew;
      lrun *= alpha;
#pragma unroll
      for (int ds = 0; ds < 8; ++ds)
#pragma unroll
        for (int r = 0; r < 16; ++r) acc[ds][r] *= alpha;
    }
    float p[16];
#pragma unroll
    for (int r = 0; r < 16; ++r) p[r] = __builtin_amdgcn_exp2f(st[r] - mrun);
    float y0 = (p[0] + p[1]) + (p[2] + p[3]);
    float y1 = (p[4] + p[5]) + (p[6] + p[7]);
    float y2 = (p[8] + p[9]) + (p[10] + p[11]);
    float y3 = (p[12] + p[13]) + (p[14] + p[15]);
    float rs = (y0 + y1) + (y2 + y3);
    rs += __shfl_xor(rs, 32);
    lrun += rs;

    // ---- pack P^T to f16; pkw[rq*2+w2] covers i = 8*rq + 4h + 2*w2 + {0,1} ----
    u32 pkw[8];
#pragma unroll
    for (int rq = 0; rq < 4; ++rq) {
      pkw[rq * 2 + 0] = pk2h(p[rq * 4 + 0], p[rq * 4 + 1]);
      pkw[rq * 2 + 1] = pk2h(p[rq * 4 + 2], p[rq * 4 + 3]);
    }
    // ---- B-frag(ic): lane needs i = ic*16 + 8h + {0..7} ----
    half8 bfr[2];
#pragma unroll
    for (int ic = 0; ic < 2; ++ic) {
      u32 own0 = pkw[(2 * ic + h) * 2 + 0];
      u32 own1 = pkw[(2 * ic + h) * 2 + 1];
      u32 send0 = pkw[(2 * ic + 1 - h) * 2 + 0];
      u32 send1 = pkw[(2 * ic + 1 - h) * 2 + 1];
      u32 r0 = (u32)__shfl_xor((int)send0, 32);
      u32 r1 = (u32)__shfl_xor((int)send1, 32);
      union { u32 u[4]; half8 v; } bb;
      bb.u[0] = h ? r0 : own0;
      bb.u[1] = h ? r1 : own1;
      bb.u[2] = h ? own0 : r0;
      bb.u[3] = h ? own1 : r1;
      bfr[ic] = bb.v;
    }

    // ---- O^T += encT . P^T ----
    const char* tb = (const char*)&lds[kh][cur][TILE_U16];
#pragma unroll
    for (int ic = 0; ic < 2; ++ic) {
#pragma unroll
      for (int ds = 0; ds < 8; ++ds) {
        half8 vf = *(const half8*)(tb + ((ds * 2 + ic) * 2 + h) * 512 + l31 * 16);
        acc[ds] = MFMA32(vf, bfr[ic], acc[ds]);
      }
    }

    __syncthreads();
  }

  // ---- merge the two K-streams through LDS ----
  float* fb = (float*)&lds[0][0][0];   // 32768 floats total
  constexpr int XS = 20;               // padded per-lane stride (floats)
  float* mlb = fb + 30208;             // m/l area (256 floats)

  if (kh == 1) {
    if (lane < 32) {
      mlb[wq * 64 + lane] = mrun;
      mlb[wq * 64 + 32 + lane] = lrun;
    }
#pragma unroll
    for (int d4 = 0; d4 < 4; ++d4) {
      float* dst = fb + ((wq * 4 + d4) * 64 + lane) * XS;
#pragma unroll
      for (int r4 = 0; r4 < 4; ++r4) {
        float4 v;
        v.x = acc[d4][r4 * 4 + 0]; v.y = acc[d4][r4 * 4 + 1];
        v.z = acc[d4][r4 * 4 + 2]; v.w = acc[d4][r4 * 4 + 3];
        *(float4*)(dst + r4 * 4) = v;
      }
    }
  }
  __syncthreads();

  float a0 = 0.f, a1 = 0.f, inv = 0.f;
  const int q = qw + l31;
  float* orow = out + ((size_t)(b * S + q)) * D;
  if (kh == 0) {
    float m1 = mlb[wq * 64 + l31];
    float l1 = mlb[wq * 64 + 32 + l31];
    float mn = fmaxf(mrun, m1);
    a0 = __builtin_amdgcn_exp2f(mrun - mn);
    a1 = __builtin_amdgcn_exp2f(m1 - mn);
    inv = 1.0f / (a0 * lrun + a1 * l1);
#pragma unroll
    for (int d4 = 0; d4 < 4; ++d4) {
      const float* src = fb + ((wq * 4 + d4) * 64 + lane) * XS;
#pragma unroll
      for (int rq = 0; rq < 4; ++rq) {
        float4 u = *(const float4*)(src + rq * 4);
        int d = d4 * 32 + rq * 8 + h * 4;
        float4 o;
        o.x = (a0 * acc[d4][rq * 4 + 0] + a1 * u.x) * inv;
        o.y = (a0 * acc[d4][rq * 4 + 1] + a1 * u.y) * inv;
        o.z = (a0 * acc[d4][rq * 4 + 2] + a1 * u.z) * inv;
        o.w = (a0 * acc[d4][rq * 4 + 3] + a1 * u.w) * inv;
        *(float4*)(orow + d) = o;
      }
    }
  }
  __syncthreads();

  if (kh == 1) {
#pragma unroll
    for (int d4 = 0; d4 < 4; ++d4) {
      float* dst = fb + ((wq * 4 + d4) * 64 + lane) * XS;
#pragma unroll
      for (int r4 = 0; r4 < 4; ++r4) {
        float4 v;
        v.x = acc[d4 + 4][r4 * 4 + 0]; v.y = acc[d4 + 4][r4 * 4 + 1];
        v.z = acc[d4 + 4][r4 * 4 + 2]; v.w = acc[d4 + 4][r4 * 4 + 3];
        *(float4*)(dst + r4 * 4) = v;
      }
    }
  }
  __syncthreads();

  if (kh == 0) {
#pragma unroll
    for (int d4 = 0; d4 < 4; ++d4) {
      const float* src = fb + ((wq * 4 + d4) * 64 + lane) * XS;
#pragma unroll
      for (int rq = 0; rq < 4; ++rq) {
        float4 u = *(const float4*)(src + rq * 4);
        int d = (d4 + 4) * 32 + rq * 8 + h * 4;
        float4 o;
        o.x = (a0 * acc[d4 + 4][rq * 4 + 0] + a1 * u.x) * inv;
        o.y = (a0 * acc[d4 + 4][rq * 4 + 1] + a1 * u.y) * inv;
        o.z = (a0 * acc[d4 + 4][rq * 4 + 2] + a1 * u.z) * inv;
        o.w = (a0 * acc[d4 + 4][rq * 4 + 3] + a1 * u.w) * inv;
        *(float4*)(orow + d) = o;
      }
    }
  }
}

// ---------------------------------------------------------------------------
extern "C" void kernel_launch(void* const* d_in, const int* in_sizes, int n_in,
                              void* d_out, int out_size, void* d_ws, size_t ws_size,
                              hipStream_t stream) {
  const float* enc = (const float*)d_in[0];
  const float* dec = (const float*)d_in[1];
  float* out = (float*)d_out;

  u16* enc_ws = (u16*)d_ws;                            // 16 MiB
  u16* encT_ws = enc_ws + (size_t)BN * NT * TILE_U16;  // 16 MiB

  convert_enc<<<BN * (S / 64), 256, 0, stream>>>(enc, enc_ws, encT_ws);
  attn_kernel<<<BN * (S / 128), 512, 0, stream>>>(enc_ws, encT_ws, dec, out);
}